// Round 1
// baseline (399.783 us; speedup 1.0000x reference)
//
#include <hip/hip_runtime.h>

// RoI Align, 14x14 output bins, bilinear, spatial_scale = 0.0625.
// features: (N=2, C=512, H=100, W=152) fp32 NCHW
// rois:     (R=512, 5) fp32  [batch_idx, x1, y1, x2, y2]
// out:      (R, C, 14, 14) fp32

#define AH 14
#define AW 14
#define NB (AH * AW)            // 196 bins per ROI (196 % 4 == 0)

constexpr int Cc  = 512;
constexpr int Hh  = 100;
constexpr int Ww  = 152;
constexpr int CPB = 128;        // channels per block -> grid.y = 4

__global__ __launch_bounds__(256)
void roi_align_kernel(const float* __restrict__ feat,
                      const float* __restrict__ rois,
                      float* __restrict__ out)
{
    const int r  = blockIdx.x;
    const int c0 = blockIdx.y * CPB;

    __shared__ int4   s_off[NB];   // 4 neighbor offsets within one channel image
    __shared__ float4 s_w[NB];     // 4 bilinear weights
    __shared__ int    s_base;      // batch base offset into features

    const float* roi = rois + r * 5;
    const float x_start = roi[1] * 0.0625f;
    const float y_start = roi[2] * 0.0625f;
    const float x_end   = roi[3] * 0.0625f;
    const float y_end   = roi[4] * 0.0625f;
    const float roi_w = fmaxf(x_end - x_start, 0.0f);
    const float roi_h = fmaxf(y_end - y_start, 0.0f);
    const float bin_h = roi_h / (float)(AH - 1);
    const float bin_w = roi_w / (float)(AW - 1);

    if (threadIdx.x == 0)
        s_base = ((int)roi[0]) * (Cc * Hh * Ww);

    for (int i = threadIdx.x; i < NB; i += blockDim.x) {
        const int ph = i / AW;
        const int pw = i - ph * AW;
        float ys = y_start + (float)ph * bin_h;
        float xs = x_start + (float)pw * bin_w;
        ys = fminf(fmaxf(ys, 0.0f), (float)(Hh - 1));
        xs = fminf(fmaxf(xs, 0.0f), (float)(Ww - 1));
        const int y0 = (int)floorf(ys);
        const int x0 = (int)floorf(xs);
        const int y1 = min(y0 + 1, Hh - 1);
        const int x1 = min(x0 + 1, Ww - 1);
        const float wy = ys - (float)y0;
        const float wx = xs - (float)x0;
        s_off[i] = make_int4(y0 * Ww + x0, y0 * Ww + x1,
                             y1 * Ww + x0, y1 * Ww + x1);
        s_w[i]   = make_float4((1.0f - wy) * (1.0f - wx),
                               (1.0f - wy) * wx,
                               wy * (1.0f - wx),
                               wy * wx);
    }
    __syncthreads();

    const int   base = s_base;
    const int   jstart = c0 * NB;
    const int   jend   = jstart + CPB * NB;
    float* __restrict__ outr = out + (size_t)r * (Cc * NB);

    // Flat index j = c*196 + bin; 4 consecutive j share one channel
    // (196 % 4 == 0), so a float4 store never crosses a channel boundary.
    for (int j = jstart + (int)threadIdx.x * 4; j < jend; j += (int)blockDim.x * 4) {
        const int c   = j / NB;
        const int bin = j - c * NB;
        const float* __restrict__ f = feat + base + c * (Hh * Ww);

        float4 v;
        {
            const int4   o = s_off[bin + 0];
            const float4 w = s_w[bin + 0];
            v.x = w.x * f[o.x] + w.y * f[o.y] + w.z * f[o.z] + w.w * f[o.w];
        }
        {
            const int4   o = s_off[bin + 1];
            const float4 w = s_w[bin + 1];
            v.y = w.x * f[o.x] + w.y * f[o.y] + w.z * f[o.z] + w.w * f[o.w];
        }
        {
            const int4   o = s_off[bin + 2];
            const float4 w = s_w[bin + 2];
            v.z = w.x * f[o.x] + w.y * f[o.y] + w.z * f[o.z] + w.w * f[o.w];
        }
        {
            const int4   o = s_off[bin + 3];
            const float4 w = s_w[bin + 3];
            v.w = w.x * f[o.x] + w.y * f[o.y] + w.z * f[o.z] + w.w * f[o.w];
        }
        *(float4*)(outr + j) = v;
    }
}

extern "C" void kernel_launch(void* const* d_in, const int* in_sizes, int n_in,
                              void* d_out, int out_size, void* d_ws, size_t ws_size,
                              hipStream_t stream)
{
    const float* feat = (const float*)d_in[0];
    const float* rois = (const float*)d_in[1];
    float*       out  = (float*)d_out;

    const int R = in_sizes[1] / 5;          // 512
    dim3 grid(R, Cc / CPB);                 // (512, 4)
    roi_align_kernel<<<grid, 256, 0, stream>>>(feat, rois, out);
}

// Round 2
// 355.658 us; speedup vs baseline: 1.1241x; 1.1241x over previous
//
#include <hip/hip_runtime.h>

// RoI Align 14x14, bilinear, spatial_scale = 0.0625.
// features: (N=2, C=512, H=100, W=152) fp32 NCHW
// rois:     (R=512, 5) fp32
// out:      (R, 512, 14, 14) fp32
//
// Strategy: NCHW -> NHWC transpose into workspace, then channel-coalesced
// gather (lane = channel), output transposed back to NCHW via padded LDS.

#define AH 14
#define AW 14
#define NB (AH * AW)            // 196

constexpr int Nn  = 2;
constexpr int Cc  = 512;
constexpr int Hh  = 100;
constexpr int Ww  = 152;
constexpr int HW  = Hh * Ww;    // 15200
constexpr int CPB = 64;         // channels per block in main kernel
constexpr int HALF = NB / 2;    // 98 bins per pass

// ---------------------------------------------------------------- transpose
// Per batch: A[C][HW] -> B[HW][C], 64x64 tiles via LDS.
__global__ __launch_bounds__(256)
void nchw_to_nhwc(const float* __restrict__ feat, float* __restrict__ nhwc)
{
    __shared__ float tile[64][65];

    const int n  = blockIdx.z;
    const int s0 = blockIdx.x * 64;
    const int c0 = blockIdx.y * 64;
    const int tx = threadIdx.x & 63;
    const int ty = threadIdx.x >> 6;        // 0..3

    const float* A = feat + (size_t)n * Cc * HW;
    float*       B = nhwc + (size_t)n * HW * Cc;

    if (s0 + tx < HW) {
        #pragma unroll
        for (int i = 0; i < 16; ++i) {
            const int cl = ty + 4 * i;
            tile[cl][tx] = A[(size_t)(c0 + cl) * HW + (s0 + tx)];
        }
    }
    __syncthreads();
    #pragma unroll
    for (int i = 0; i < 16; ++i) {
        const int sl = ty + 4 * i;
        if (s0 + sl < HW)
            B[(size_t)(s0 + sl) * Cc + (c0 + tx)] = tile[tx][sl];
    }
}

// ---------------------------------------------------------------- main
__global__ __launch_bounds__(256)
void roi_align_nhwc(const float* __restrict__ nhwc,
                    const float* __restrict__ rois,
                    float* __restrict__ out)
{
    const int r    = blockIdx.x;
    const int c0   = blockIdx.y * CPB;
    const int tid  = threadIdx.x;
    const int lane = tid & 63;
    const int wid  = tid >> 6;

    __shared__ int4   s_off[NB];          // neighbor offsets, units: floats (scaled by C)
    __shared__ float4 s_w[NB];
    __shared__ int    s_base;
    __shared__ float  tile[HALF * 65];    // [bin_local][c_local], stride 65

    const float* roi = rois + r * 5;
    const float x_start = roi[1] * 0.0625f;
    const float y_start = roi[2] * 0.0625f;
    const float roi_w = fmaxf(roi[3] * 0.0625f - x_start, 0.0f);
    const float roi_h = fmaxf(roi[4] * 0.0625f - y_start, 0.0f);
    const float bin_h = roi_h / (float)(AH - 1);
    const float bin_w = roi_w / (float)(AW - 1);

    if (tid == 0)
        s_base = ((int)roi[0]) * (HW * Cc);

    if (tid < NB) {
        const int ph = tid / AW;
        const int pw = tid - ph * AW;
        float ys = y_start + (float)ph * bin_h;
        float xs = x_start + (float)pw * bin_w;
        ys = fminf(fmaxf(ys, 0.0f), (float)(Hh - 1));
        xs = fminf(fmaxf(xs, 0.0f), (float)(Ww - 1));
        const int y0 = (int)floorf(ys);
        const int x0 = (int)floorf(xs);
        const int y1 = min(y0 + 1, Hh - 1);
        const int x1 = min(x0 + 1, Ww - 1);
        const float wy = ys - (float)y0;
        const float wx = xs - (float)x0;
        s_off[tid] = make_int4((y0 * Ww + x0) << 9, (y0 * Ww + x1) << 9,
                               (y1 * Ww + x0) << 9, (y1 * Ww + x1) << 9);
        s_w[tid]   = make_float4((1.0f - wy) * (1.0f - wx),
                                 (1.0f - wy) * wx,
                                 wy * (1.0f - wx),
                                 wy * wx);
    }
    __syncthreads();

    const float* fb = nhwc + s_base + c0 + lane;   // lane = channel within group
    float* __restrict__ outr = out + (size_t)r * (Cc * NB);

    #pragma unroll
    for (int pass = 0; pass < 2; ++pass) {
        // compute: wave handles bins pass*98 + {wid, wid+4, ...}
        for (int bl = wid; bl < HALF; bl += 4) {
            const int bin = pass * HALF + bl;
            const int4   o = s_off[bin];
            const float4 w = s_w[bin];
            const float v = w.x * fb[o.x] + w.y * fb[o.y]
                          + w.z * fb[o.z] + w.w * fb[o.w];
            tile[bl * 65 + lane] = v;
        }
        __syncthreads();
        // write back NCHW, coalesced
        #pragma unroll
        for (int k = 0; k < 25; ++k) {
            const int idx = k * 256 + tid;        // 0 .. 6271
            if (idx < HALF * CPB) {
                const int cl = idx / HALF;
                const int bl = idx - cl * HALF;
                outr[(c0 + cl) * NB + pass * HALF + bl] = tile[bl * 65 + cl];
            }
        }
        __syncthreads();
    }
}

// ---------------------------------------------------------------- fallback
// (used only if workspace is too small for the NHWC copy)
__global__ __launch_bounds__(256)
void roi_align_nchw(const float* __restrict__ feat,
                    const float* __restrict__ rois,
                    float* __restrict__ out)
{
    const int r  = blockIdx.x;
    const int c0 = blockIdx.y * 128;

    __shared__ int4   s_off[NB];
    __shared__ float4 s_w[NB];
    __shared__ int    s_base;

    const float* roi = rois + r * 5;
    const float x_start = roi[1] * 0.0625f;
    const float y_start = roi[2] * 0.0625f;
    const float roi_w = fmaxf(roi[3] * 0.0625f - x_start, 0.0f);
    const float roi_h = fmaxf(roi[4] * 0.0625f - y_start, 0.0f);
    const float bin_h = roi_h / (float)(AH - 1);
    const float bin_w = roi_w / (float)(AW - 1);

    if (threadIdx.x == 0)
        s_base = ((int)roi[0]) * (Cc * HW);

    for (int i = threadIdx.x; i < NB; i += blockDim.x) {
        const int ph = i / AW;
        const int pw = i - ph * AW;
        float ys = y_start + (float)ph * bin_h;
        float xs = x_start + (float)pw * bin_w;
        ys = fminf(fmaxf(ys, 0.0f), (float)(Hh - 1));
        xs = fminf(fmaxf(xs, 0.0f), (float)(Ww - 1));
        const int y0 = (int)floorf(ys);
        const int x0 = (int)floorf(xs);
        const int y1 = min(y0 + 1, Hh - 1);
        const int x1 = min(x0 + 1, Ww - 1);
        const float wy = ys - (float)y0;
        const float wx = xs - (float)x0;
        s_off[i] = make_int4(y0 * Ww + x0, y0 * Ww + x1,
                             y1 * Ww + x0, y1 * Ww + x1);
        s_w[i]   = make_float4((1.0f - wy) * (1.0f - wx),
                               (1.0f - wy) * wx,
                               wy * (1.0f - wx),
                               wy * wx);
    }
    __syncthreads();

    const int base = s_base;
    float* __restrict__ outr = out + (size_t)r * (Cc * NB);
    const int jend = (c0 + 128) * NB;
    for (int j = c0 * NB + (int)threadIdx.x * 4; j < jend; j += 256 * 4) {
        const int c   = j / NB;
        const int bin = j - c * NB;
        const float* f = feat + base + c * HW;
        float4 v;
        {
            const int4 o = s_off[bin];     const float4 w = s_w[bin];
            v.x = w.x*f[o.x] + w.y*f[o.y] + w.z*f[o.z] + w.w*f[o.w];
        }
        {
            const int4 o = s_off[bin + 1]; const float4 w = s_w[bin + 1];
            v.y = w.x*f[o.x] + w.y*f[o.y] + w.z*f[o.z] + w.w*f[o.w];
        }
        {
            const int4 o = s_off[bin + 2]; const float4 w = s_w[bin + 2];
            v.z = w.x*f[o.x] + w.y*f[o.y] + w.z*f[o.z] + w.w*f[o.w];
        }
        {
            const int4 o = s_off[bin + 3]; const float4 w = s_w[bin + 3];
            v.w = w.x*f[o.x] + w.y*f[o.y] + w.z*f[o.z] + w.w*f[o.w];
        }
        *(float4*)(outr + j) = v;
    }
}

extern "C" void kernel_launch(void* const* d_in, const int* in_sizes, int n_in,
                              void* d_out, int out_size, void* d_ws, size_t ws_size,
                              hipStream_t stream)
{
    const float* feat = (const float*)d_in[0];
    const float* rois = (const float*)d_in[1];
    float*       out  = (float*)d_out;
    const int R = in_sizes[1] / 5;                       // 512

    const size_t need = (size_t)Nn * HW * Cc * sizeof(float);   // 62.26 MB
    if (ws_size >= need) {
        float* nhwc = (float*)d_ws;
        dim3 tg((HW + 63) / 64, Cc / 64, Nn);            // (238, 8, 2)
        nchw_to_nhwc<<<tg, 256, 0, stream>>>(feat, nhwc);
        dim3 mg(R, Cc / CPB);                            // (512, 8)
        roi_align_nhwc<<<mg, 256, 0, stream>>>(nhwc, rois, out);
    } else {
        dim3 grid(R, Cc / 128);
        roi_align_nchw<<<grid, 256, 0, stream>>>(feat, rois, out);
    }
}